// Round 10
// baseline (188.049 us; speedup 1.0000x reference)
//
#include <hip/hip_runtime.h>
#include <hip/hip_bf16.h>

// ---------------------------------------------------------------------------
// SimpleSelfAttention: out = softmax((xWq^T+bq)(xWk^T+bk)^T / 32) (xWv^T+bv)
// B=4, S=2048, E=1024, fp32 in/out. Internally bf16 MFMA, fp32 accum.
//
// GEMM core (gemm97 = m97 replica): 128x128 tile, BK=64, 4 waves (256 thr),
// wave out 64x64 (4x4 frags), SINGLE 32KB LDS buffer -> 3 blocks/CU
// (implicit cross-block wave overlap hides the barrier drain, m114).
// Per K-step: {lgkmcnt0+barrier} stage (8 gload_lds16/thr) {vmcnt0+barrier}
// 16 ds_read_b128 + 32 MFMA. Swizzle: 16B chunk c of row r at c ^ (r&7)
// (involution; validated in R8). XCD-aware bijective block swizzle on
// flattened (x,y): id2 = (id%8)*(nwg/8) + id/8, nwg%8==0 for all grids.
//
// Pipeline (R9-proven): no transpose, no final memcpy.
//   ws: Q@0 (16MB) | K@8M1 (16MB) | P@16M1 (32MB) ; VT@8M1 over dead K
//   d_out scratch: xb@0 (16MB) | Wb@8M1 (6MB)  [last read by VT-GEMM]
//   cvt -> QK proj (z=2) -> scores -> VT = Wv xb^T + bv (row bias, z=4)
//       -> softmax -> PV (fp32 direct to d_out)
// ---------------------------------------------------------------------------

typedef __attribute__((ext_vector_type(8))) short bf16x8;
typedef __attribute__((ext_vector_type(4))) float f32x4;

#define DEVI static __device__ __forceinline__

DEVI short to_bf16(float f) {
    unsigned u = __builtin_bit_cast(unsigned, f);
    u += 0x7fffu + ((u >> 16) & 1u);          // RNE (finite/normal inputs)
    return (short)(u >> 16);
}
DEVI float from_bf16(short s) {
    return __builtin_bit_cast(float, (unsigned)((unsigned short)s) << 16);
}

DEVI void gload_lds16(const short* g, short* l) {
    __builtin_amdgcn_global_load_lds(
        (const __attribute__((address_space(1))) void*)g,
        (__attribute__((address_space(3))) void*)l, 16, 0, 0);
}

// C[z][M][N] = scale * A[z].B[z]^T (+ bias). A,B bf16 K-major. K%64==0.
// BIAS: 0=none, 1=col bias b_z[n] (z-selected), 2=row bias b0[m] (all z).
// Output ptr z-selected from {c0,c1,c2} + z*bsC (batched: c0=c1=c2).
template<int BIAS, typename TOUT>
__global__ __launch_bounds__(256, 3)
void gemm97(const short* __restrict__ A, long lda, long bsA,
            const short* __restrict__ B, long ldb, long bsB,
            const float* __restrict__ b0, const float* __restrict__ b1,
            const float* __restrict__ b2,
            TOUT* __restrict__ c0, TOUT* __restrict__ c1, TOUT* __restrict__ c2,
            long ldc, long bsC, int K, float scale)
{
    __shared__ __align__(16) short As[128 * 64];   // [row][64], swizzled chunks
    __shared__ __align__(16) short Bs[128 * 64];

    const int tid = threadIdx.x;
    const int z = blockIdx.z;

    // XCD-aware bijective swizzle of the flattened per-z grid (nwg % 8 == 0)
    const int gx = gridDim.x;
    const int nwg = gx * gridDim.y;
    const int id = blockIdx.y * gx + blockIdx.x;
    const int id2 = (id & 7) * (nwg >> 3) + (id >> 3);
    const long m0 = (long)(id2 / gx) * 128;
    const long n0 = (long)(id2 % gx) * 128;

    const short* Ab = A + (long)z * bsA + m0 * lda;
    const short* Bb = B + (long)z * bsB + n0 * ldb;

    const int wv = tid >> 6;
    const int lane = tid & 63;
    const int wr = (wv >> 1) * 64;     // wave's 64x64 sub-tile
    const int wc = (wv & 1) * 64;
    const int lrow = lane & 15;
    const int q = lane >> 4;           // k-quarter (8 contiguous k elems)

    const int NT = K >> 6;             // BK=64

    // stage K-tile t: A and B 128x64 tiles, 4+4 gload_lds16 per thread.
    // thread covers 16B chunk s = i*256+tid: row = s>>3, lds chunk = s&7,
    // source chunk = (s&7) ^ (row&7)  (involution; ds_read applies same XOR)
    auto stage = [&](int t) {
        const long k0 = (long)t * 64;
        #pragma unroll
        for (int i = 0; i < 4; ++i) {
            int s = i * 256 + tid;
            int row = s >> 3;
            int src = (s & 7) ^ (row & 7);
            gload_lds16(Ab + (long)row * lda + k0 + src * 8, &As[s * 8]);
        }
        #pragma unroll
        for (int i = 0; i < 4; ++i) {
            int s = i * 256 + tid;
            int row = s >> 3;
            int src = (s & 7) ^ (row & 7);
            gload_lds16(Bb + (long)row * ldb + k0 + src * 8, &Bs[s * 8]);
        }
    };

    f32x4 acc[4][4] = {};

    for (int t = 0; t < NT; ++t) {
        if (t) {
            // this wave's frag reads are consumed (lgkm waits precede MFMAs);
            // barrier: ALL waves done reading before anyone restages.
            asm volatile("s_waitcnt lgkmcnt(0)" ::: "memory");
            __builtin_amdgcn_sched_barrier(0);
            __builtin_amdgcn_s_barrier();
        }
        stage(t);
        asm volatile("s_waitcnt vmcnt(0)" ::: "memory");
        __builtin_amdgcn_sched_barrier(0);
        __builtin_amdgcn_s_barrier();

        bf16x8 af[4][2], bf[4][2];
        #pragma unroll
        for (int m = 0; m < 4; ++m) {
            int row = wr + m * 16 + lrow;
            #pragma unroll
            for (int kk = 0; kk < 2; ++kk) {
                int ch = (kk * 4 + q) ^ (row & 7);
                af[m][kk] = *(const bf16x8*)&As[row * 64 + ch * 8];
            }
        }
        #pragma unroll
        for (int n = 0; n < 4; ++n) {
            int row = wc + n * 16 + lrow;
            #pragma unroll
            for (int kk = 0; kk < 2; ++kk) {
                int ch = (kk * 4 + q) ^ (row & 7);
                bf[n][kk] = *(const bf16x8*)&Bs[row * 64 + ch * 8];
            }
        }

        __builtin_amdgcn_s_setprio(1);
        #pragma unroll
        for (int m = 0; m < 4; ++m)
            #pragma unroll
            for (int n = 0; n < 4; ++n)
                #pragma unroll
                for (int kk = 0; kk < 2; ++kk)
                    acc[m][n] = __builtin_amdgcn_mfma_f32_16x16x32_bf16(
                        af[m][kk], bf[n][kk], acc[m][n], 0, 0, 0);
        __builtin_amdgcn_s_setprio(0);
    }

    // C/D layout (verified m89): col = lane&15, row = (lane>>4)*4 + reg
    const float* bias = (BIAS == 2) ? b0
                      : ((z == 0) ? b0 : (z == 1) ? b1 : b2);
    TOUT* Cz = ((z == 0) ? c0 : (z == 1) ? c1 : c2) + (long)z * bsC;
    TOUT* Cb = Cz + m0 * ldc + n0;
    #pragma unroll
    for (int m = 0; m < 4; ++m) {
        #pragma unroll
        for (int n = 0; n < 4; ++n) {
            #pragma unroll
            for (int r = 0; r < 4; ++r) {
                int row = wr + m * 16 + q * 4 + r;
                int col = wc + n * 16 + lrow;
                float v = acc[m][n][r] * scale;
                if constexpr (BIAS == 1) v += bias[n0 + col];
                if constexpr (BIAS == 2) v += bias[m0 + row];
                if constexpr (sizeof(TOUT) == 2)
                    Cb[(long)row * ldc + col] = to_bf16(v);
                else
                    Cb[(long)row * ldc + col] = v;
            }
        }
    }
}

// fp32 -> bf16, 8 elems/thread
__global__ __launch_bounds__(256)
void cvt_f32_bf16(const float* __restrict__ src, short* __restrict__ dst, int n8)
{
    int i = blockIdx.x * 256 + threadIdx.x;
    if (i < n8) {
        float4 a = ((const float4*)src)[2 * i];
        float4 b = ((const float4*)src)[2 * i + 1];
        bf16x8 o = { to_bf16(a.x), to_bf16(a.y), to_bf16(a.z), to_bf16(a.w),
                     to_bf16(b.x), to_bf16(b.y), to_bf16(b.z), to_bf16(b.w) };
        *(bf16x8*)&dst[i * 8] = o;
    }
}

// three fp32 srcs -> contiguous bf16 dst (blockIdx.y selects src)
__global__ __launch_bounds__(256)
void cvt3_f32_bf16(const float* __restrict__ s0, const float* __restrict__ s1,
                   const float* __restrict__ s2, short* __restrict__ dst, int n8)
{
    int zz = blockIdx.y;
    const float* src = (zz == 0) ? s0 : (zz == 1) ? s1 : s2;
    int i = blockIdx.x * 256 + threadIdx.x;
    if (i < n8) {
        float4 a = ((const float4*)src)[2 * i];
        float4 b = ((const float4*)src)[2 * i + 1];
        bf16x8 o = { to_bf16(a.x), to_bf16(a.y), to_bf16(a.z), to_bf16(a.w),
                     to_bf16(b.x), to_bf16(b.y), to_bf16(b.z), to_bf16(b.w) };
        *(bf16x8*)&dst[(long)zz * n8 * 8 + i * 8] = o;
    }
}

// In-place row softmax over bf16 rows of length 2048. One block/row.
__global__ __launch_bounds__(256)
void softmax_rows(short* __restrict__ S, int ncols)
{
    const long row = blockIdx.x;
    short* p = S + row * (long)ncols;
    const int t = threadIdx.x;

    union { bf16x8 v; short s[8]; } u;
    u.v = *(const bf16x8*)&p[t * 8];
    float f[8];
    float m = -3.0e38f;
    #pragma unroll
    for (int j = 0; j < 8; ++j) { f[j] = from_bf16(u.s[j]); m = fmaxf(m, f[j]); }
    #pragma unroll
    for (int off = 32; off > 0; off >>= 1) m = fmaxf(m, __shfl_xor(m, off));

    __shared__ float red[8];
    const int wave = t >> 6;
    if ((t & 63) == 0) red[wave] = m;
    __syncthreads();
    m = fmaxf(fmaxf(red[0], red[1]), fmaxf(red[2], red[3]));

    float sum = 0.f;
    #pragma unroll
    for (int j = 0; j < 8; ++j) { f[j] = __expf(f[j] - m); sum += f[j]; }
    #pragma unroll
    for (int off = 32; off > 0; off >>= 1) sum += __shfl_xor(sum, off);
    if ((t & 63) == 0) red[4 + wave] = sum;
    __syncthreads();
    sum = red[4] + red[5] + red[6] + red[7];

    const float inv = 1.0f / sum;
    #pragma unroll
    for (int j = 0; j < 8; ++j) u.s[j] = to_bf16(f[j] * inv);
    *(bf16x8*)&p[t * 8] = u.v;
}

extern "C" void kernel_launch(void* const* d_in, const int* in_sizes, int n_in,
                              void* d_out, int out_size, void* d_ws, size_t ws_size,
                              hipStream_t stream)
{
    (void)in_sizes; (void)n_in; (void)out_size; (void)ws_size;

    const float* x  = (const float*)d_in[0];
    const float* Wq = (const float*)d_in[1];
    const float* bq = (const float*)d_in[2];
    const float* Wk = (const float*)d_in[3];
    const float* bk = (const float*)d_in[4];
    const float* Wv = (const float*)d_in[5];
    const float* bv = (const float*)d_in[6];
    float* out = (float*)d_out;

    const int S = 2048, E = 1024;
    const long M1 = 1024l * 1024;

    // ws regions (shorts)
    short* w  = (short*)d_ws;
    short* Q  = w;                  // [4][2048][1024]  (16MB)
    short* Kb = w + 8 * M1;         // [4][2048][1024]  (16MB)
    short* P  = w + 16 * M1;        // [4][2048][2048]  (32MB)
    short* VT = w + 8 * M1;         // [4][1024][2048]  over dead K (post-scores)

    // d_out scratch (last read by VT-GEMM, dead before PV writes d_out)
    short* dows = (short*)d_out;
    short* xb = dows;               // [8192][1024] bf16 (16MB)
    short* Wb = dows + 8 * M1;      // Wq,Wk,Wv bf16 (3 x 2MB)

    dim3 blk(256);

    // 1. convert inputs to bf16
    cvt_f32_bf16<<<dim3(4096), blk, 0, stream>>>(x, xb, (int)M1);
    cvt3_f32_bf16<<<dim3(512, 3), blk, 0, stream>>>(Wq, Wk, Wv, Wb, (int)(M1 / 8));

    // 2. Q,K projections (M=8192, N=1024, K=1024): grid 8x64x2 = 1024 blocks
    gemm97<1, short><<<dim3(8, 64, 2), blk, 0, stream>>>(
        xb, E, 0, Wb, E, M1, bq, bk, nullptr, Q, Kb, nullptr, E, 0, E, 1.0f);

    // 3. scores: P[z] = Q[z] K[z]^T / 32 (M=N=2048, K=1024): 16x16x4 = 1024
    gemm97<0, short><<<dim3(16, 16, 4), blk, 0, stream>>>(
        Q, E, 2 * M1, Kb, E, 2 * M1, nullptr, nullptr, nullptr,
        P, P, P, S, 4 * M1, E, 0.03125f);

    // 4. VT[z] = Wv xb[z]^T + bv (row bias)  (M=1024, N=2048, K=1024)
    //    into ws over dead K: grid 16x8x4 = 512 blocks
    gemm97<2, short><<<dim3(16, 8, 4), blk, 0, stream>>>(
        Wb + 2 * M1, E, 0, xb, E, 2 * M1, bv, nullptr, nullptr,
        VT, VT, VT, S, 2 * M1, E, 1.0f);

    // 5. softmax rows in place
    softmax_rows<<<dim3(4 * S), blk, 0, stream>>>(P, S);

    // 6. out[z] = P[z] VT[z]^T (M=2048, N=1024, K=2048): 8x16x4 = 512, fp32
    gemm97<0, float><<<dim3(8, 16, 4), blk, 0, stream>>>(
        P, S, 4 * M1, VT, S, 2 * M1, nullptr, nullptr, nullptr,
        out, out, out, E, 2 * M1, S, 1.0f);
}